// Round 2
// baseline (1986.548 us; speedup 1.0000x reference)
//
#include <hip/hip_runtime.h>
#include <hip/hip_bf16.h>
#include <math.h>

#define D_    1024
#define DI_   2048
#define DS_   16
#define DTR_  64
#define B_    2
#define L_    4096
#define ROWS_ (B_ * L_)          // 8192
#define NXZ_  (2 * DI_)          // 4096

// ---------------------------------------------------------------------------
// k1: xz = x @ W_in  (M=8192, K=1024, N=4096), split into xs_raw / z halves.
// fp32, 64x64 tile, K-step 16, 4x4 per thread.
// ---------------------------------------------------------------------------
__global__ __launch_bounds__(256) void k1_gemm_in(const float* __restrict__ x,
                                                  const float* __restrict__ Win,
                                                  float* __restrict__ xs_raw,
                                                  float* __restrict__ z) {
    const int t  = threadIdx.x;
    const int m0 = blockIdx.x * 64;
    const int n0 = blockIdx.y * 64;
    __shared__ float As[16][68];
    __shared__ float Bs[16][64];
    float acc[4][4] = {};
    const int tm = (t >> 4) * 4;
    const int tn = (t & 15) * 4;
    for (int k0 = 0; k0 < D_; k0 += 16) {
        {   // A tile: 64 rows x 16 k, one float4/thread, store transposed
            const int am = t >> 2, av = t & 3;
            const float4 v = *(const float4*)(x + (size_t)(m0 + am) * D_ + k0 + av * 4);
            As[av * 4 + 0][am] = v.x; As[av * 4 + 1][am] = v.y;
            As[av * 4 + 2][am] = v.z; As[av * 4 + 3][am] = v.w;
        }
        {   // B tile: 16 k x 64 cols
            const int bk = t >> 4, bn = t & 15;
            *(float4*)&Bs[bk][bn * 4] =
                *(const float4*)(Win + (size_t)(k0 + bk) * NXZ_ + n0 + bn * 4);
        }
        __syncthreads();
#pragma unroll
        for (int k = 0; k < 16; ++k) {
            const float4 a = *(const float4*)&As[k][tm];
            const float4 b = *(const float4*)&Bs[k][tn];
            const float av_[4] = {a.x, a.y, a.z, a.w};
            const float bv_[4] = {b.x, b.y, b.z, b.w};
#pragma unroll
            for (int i = 0; i < 4; ++i)
#pragma unroll
                for (int j = 0; j < 4; ++j) acc[i][j] += av_[i] * bv_[j];
        }
        __syncthreads();
    }
#pragma unroll
    for (int i = 0; i < 4; ++i) {
        const int row = m0 + tm + i;
#pragma unroll
        for (int j = 0; j < 4; ++j) {
            const int col = n0 + tn + j;
            if (col < DI_) xs_raw[(size_t)row * DI_ + col] = acc[i][j];
            else           z[(size_t)row * DI_ + (col - DI_)] = acc[i][j];
        }
    }
}

// ---------------------------------------------------------------------------
// k2: depthwise conv(k=3, same) along L + silu + row mean (xm). 1 block/row.
// ---------------------------------------------------------------------------
__global__ __launch_bounds__(256) void k2_conv(const float* __restrict__ xs_raw,
                                               const float* __restrict__ Wcv,
                                               float* __restrict__ xs,
                                               float* __restrict__ xm) {
    const int row = blockIdx.x;          // b*L + l
    const int l   = row & (L_ - 1);
    const int t   = threadIdx.x;
    const float* cur = xs_raw + (size_t)row * DI_;
    const bool hasP = (l > 0), hasN = (l < L_ - 1);
    float lsum = 0.f;
    for (int c = t; c < DI_; c += 256) {
        const float w0 = Wcv[c * 3 + 0], w1 = Wcv[c * 3 + 1], w2 = Wcv[c * 3 + 2];
        float v = cur[c] * w1;
        if (hasP) v += cur[c - DI_] * w0;
        if (hasN) v += cur[c + DI_] * w2;
        const float s = v / (1.f + expf(-v));          // silu
        xs[(size_t)row * DI_ + c] = s;
        lsum += s;
    }
    __shared__ float red[256];
    red[t] = lsum;
    __syncthreads();
    for (int s = 128; s > 0; s >>= 1) {
        if (t < s) red[t] += red[t + s];
        __syncthreads();
    }
    if (t == 0) xm[row] = red[0] * (1.f / (float)DI_);
}

// ---------------------------------------------------------------------------
// k3: xp = xs @ W_xproj  (M=8192, K=2048, N=96). 64x96 tile, K-step 32.
// ---------------------------------------------------------------------------
__global__ __launch_bounds__(256) void k3_xproj(const float* __restrict__ xs,
                                                const float* __restrict__ Wxp,
                                                float* __restrict__ xp) {
    const int t  = threadIdx.x;
    const int m0 = blockIdx.x * 64;
    __shared__ float As[32][68];
    __shared__ float Bs[32][96];
    float acc[4][6] = {};
    const int tm = (t >> 4) * 4;
    const int tn = (t & 15) * 6;
    for (int k0 = 0; k0 < DI_; k0 += 32) {
#pragma unroll
        for (int i = 0; i < 2; ++i) {   // A: 64 rows x 32 k = 512 float4
            const int f = t + 256 * i;
            const int am = f >> 3, av = f & 7;
            const float4 v = *(const float4*)(xs + (size_t)(m0 + am) * DI_ + k0 + av * 4);
            As[av * 4 + 0][am] = v.x; As[av * 4 + 1][am] = v.y;
            As[av * 4 + 2][am] = v.z; As[av * 4 + 3][am] = v.w;
        }
#pragma unroll
        for (int i = 0; i < 12; ++i) {  // B: 32 k x 96
            const int e = t + 256 * i;
            const int bk = e / 96, bn = e - bk * 96;
            Bs[bk][bn] = Wxp[(size_t)(k0 + bk) * 96 + bn];
        }
        __syncthreads();
#pragma unroll
        for (int k = 0; k < 32; ++k) {
            float a[4], b[6];
#pragma unroll
            for (int i = 0; i < 4; ++i) a[i] = As[k][tm + i];
#pragma unroll
            for (int j = 0; j < 6; ++j) b[j] = Bs[k][tn + j];
#pragma unroll
            for (int i = 0; i < 4; ++i)
#pragma unroll
                for (int j = 0; j < 6; ++j) acc[i][j] += a[i] * b[j];
        }
        __syncthreads();
    }
#pragma unroll
    for (int i = 0; i < 4; ++i)
#pragma unroll
        for (int j = 0; j < 6; ++j)
            xp[(size_t)(m0 + tm + i) * 96 + tn + j] = acc[i][j];
}

// ---------------------------------------------------------------------------
// k4: dtm = mean_i softplus(dt_lo @ W_dt + b_dt);  dec = exp(-dtm);
//     u = xm * sum(Bp).   32 rows/block, never materializes dt.
// ---------------------------------------------------------------------------
__global__ __launch_bounds__(256) void k4_dt(const float* __restrict__ xp,
                                             const float* __restrict__ Wdt,
                                             const float* __restrict__ bdt,
                                             const float* __restrict__ xm,
                                             float* __restrict__ dec,
                                             float* __restrict__ u) {
    const int r0 = blockIdx.x * 32;
    const int t  = threadIdx.x;
    __shared__ float dlo[32][64];
    __shared__ float Wc[64][65];
    __shared__ float red[32][64];
#pragma unroll
    for (int i = 0; i < 8; ++i) {       // dt_lo tile: 32 rows x 64
        const int e = t + 256 * i;
        const int r = e >> 6, k = e & 63;
        dlo[r][k] = xp[(size_t)(r0 + r) * 96 + k];
    }
    float acc[8] = {};
    const int i_l   = t & 63;
    const int rbase = t >> 6;
    for (int i0 = 0; i0 < DI_; i0 += 64) {
        __syncthreads();
#pragma unroll
        for (int ii = 0; ii < 16; ++ii) {  // W_dt chunk: 64 k x 64 i
            const int e = t + 256 * ii;
            const int wk = e >> 6, wi = e & 63;
            Wc[wk][wi] = Wdt[(size_t)wk * DI_ + i0 + wi];
        }
        __syncthreads();
        const float bb = bdt[i0 + i_l];
#pragma unroll
        for (int j = 0; j < 8; ++j) {
            const int r = rbase + 4 * j;
            float w = bb;
#pragma unroll
            for (int k = 0; k < 64; ++k) w += dlo[r][k] * Wc[k][i_l];
            acc[j] += fmaxf(w, 0.f) + log1pf(expf(-fabsf(w)));  // softplus
        }
    }
    __syncthreads();
#pragma unroll
    for (int j = 0; j < 8; ++j) red[rbase + 4 * j][i_l] = acc[j];
    __syncthreads();
    if (t < 32) {
        float tot = 0.f;
        for (int i = 0; i < 64; ++i) tot += red[t][i];
        const float dtm = tot * (1.f / (float)DI_);
        float sBp = 0.f;
        for (int s = 0; s < DS_; ++s) sBp += xp[(size_t)(r0 + t) * 96 + DTR_ + s];
        dec[r0 + t] = expf(-dtm);
        u[r0 + t]   = xm[r0 + t] * sBp;
    }
}

// ---------------------------------------------------------------------------
// k5: exact chunked scalar scan  S_l = d_l * S_{l-1} + u_l  (per batch).
// One block: 256 chunks (2 batches x 128) of length 32, 3 phases.
// ---------------------------------------------------------------------------
__global__ __launch_bounds__(256) void k5_scan(const float* __restrict__ dec,
                                               const float* __restrict__ u,
                                               float* __restrict__ S) {
    const int t = threadIdx.x;
    __shared__ float aa[256], hh[256], init[256];
    const int b = t >> 7, c = t & 127;
    const int base = b * L_ + c * 32;
    float a = 1.f, h = 0.f;
    for (int i = 0; i < 32; ++i) {
        const float d = dec[base + i];
        h = h * d + u[base + i];
        a *= d;
    }
    aa[t] = a; hh[t] = h;
    __syncthreads();
    if (t < B_) {
        float run = 0.f;
        for (int cc = 0; cc < 128; ++cc) {
            const int tt = t * 128 + cc;
            init[tt] = run;
            run = hh[tt] + aa[tt] * run;
        }
    }
    __syncthreads();
    h = init[t];
    for (int i = 0; i < 32; ++i) {
        h = h * dec[base + i] + u[base + i];
        S[base + i] = h;
    }
}

// ---------------------------------------------------------------------------
// k6: per-row 16-vector v = Cp*S, LayerNorm stats over 16 (== LN over the
// 2048 tile), store normalized v16.
// ---------------------------------------------------------------------------
__global__ __launch_bounds__(256) void k6_v16(const float* __restrict__ xp,
                                              const float* __restrict__ S,
                                              float* __restrict__ v16) {
    const int row = blockIdx.x * 256 + threadIdx.x;   // 8192 rows
    const float s = S[row];
    float v[16], mu = 0.f;
#pragma unroll
    for (int i = 0; i < 16; ++i) {
        v[i] = xp[(size_t)row * 96 + DTR_ + DS_ + i] * s;
        mu += v[i];
    }
    mu *= (1.f / 16.f);
    float var = 0.f;
#pragma unroll
    for (int i = 0; i < 16; ++i) {
        const float d = v[i] - mu;
        var += d * d;
    }
    var *= (1.f / 16.f);
    const float rs = rsqrtf(var + 1e-5f);
#pragma unroll
    for (int i = 0; i < 16; ++i) v16[(size_t)row * 16 + i] = (v[i] - mu) * rs;
}

// ---------------------------------------------------------------------------
// k7: out = A @ W_out (M=8192, K=2048, N=1024), A generated on the fly:
//     A[row,i] = (v16[row][i&15]*g[i] + b[i]) * silu(z[row,i]).  fp32 out.
// ---------------------------------------------------------------------------
__global__ __launch_bounds__(256) void k7_out(const float* __restrict__ z,
                                              const float* __restrict__ v16,
                                              const float* __restrict__ g,
                                              const float* __restrict__ bb,
                                              const float* __restrict__ Wout,
                                              float* __restrict__ out) {
    const int t  = threadIdx.x;
    const int m0 = blockIdx.x * 64;
    const int n0 = blockIdx.y * 64;
    __shared__ float As[16][68];
    __shared__ float Bs[16][64];
    __shared__ float v16s[64][16];
#pragma unroll
    for (int i = 0; i < 4; ++i) {
        const int e = t + 256 * i;
        const int r = e >> 4, s = e & 15;
        v16s[r][s] = v16[(size_t)(m0 + r) * 16 + s];
    }
    __syncthreads();
    float acc[4][4] = {};
    const int tm = (t >> 4) * 4;
    const int tn = (t & 15) * 4;
    for (int k0 = 0; k0 < DI_; k0 += 16) {
        {
            const int am = t >> 2, av = t & 3;
            const float4 zv = *(const float4*)(z + (size_t)(m0 + am) * DI_ + k0 + av * 4);
            const float zz[4] = {zv.x, zv.y, zv.z, zv.w};
#pragma unroll
            for (int j = 0; j < 4; ++j) {
                const int i = k0 + av * 4 + j;
                const float sz = zz[j] / (1.f + expf(-zz[j]));
                As[av * 4 + j][am] = (v16s[am][i & 15] * g[i] + bb[i]) * sz;
            }
        }
        {
            const int bk = t >> 4, bn = t & 15;
            *(float4*)&Bs[bk][bn * 4] =
                *(const float4*)(Wout + (size_t)(k0 + bk) * D_ + n0 + bn * 4);
        }
        __syncthreads();
#pragma unroll
        for (int k = 0; k < 16; ++k) {
            const float4 a = *(const float4*)&As[k][tm];
            const float4 b = *(const float4*)&Bs[k][tn];
            const float av_[4] = {a.x, a.y, a.z, a.w};
            const float bv_[4] = {b.x, b.y, b.z, b.w};
#pragma unroll
            for (int i = 0; i < 4; ++i)
#pragma unroll
                for (int j = 0; j < 4; ++j) acc[i][j] += av_[i] * bv_[j];
        }
        __syncthreads();
    }
#pragma unroll
    for (int i = 0; i < 4; ++i)
#pragma unroll
        for (int j = 0; j < 4; ++j)
            out[(size_t)(m0 + tm + i) * D_ + n0 + tn + j] = acc[i][j];
}

// ---------------------------------------------------------------------------
extern "C" void kernel_launch(void* const* d_in, const int* in_sizes, int n_in,
                              void* d_out, int out_size, void* d_ws, size_t ws_size,
                              hipStream_t stream) {
    const float* x    = (const float*)d_in[0];
    const float* Win  = (const float*)d_in[1];
    const float* Wcv  = (const float*)d_in[2];
    const float* Wxp  = (const float*)d_in[3];
    const float* Wdt  = (const float*)d_in[4];
    const float* bdt  = (const float*)d_in[5];
    const float* Wout = (const float*)d_in[6];
    const float* lng  = (const float*)d_in[7];
    const float* lnb  = (const float*)d_in[8];
    float* out = (float*)d_out;

    // workspace layout (floats); total ~206 MB
    float* ws     = (float*)d_ws;
    float* xs_raw = ws;                         // 16777216
    float* z      = xs_raw + (size_t)ROWS_ * DI_;  // 16777216
    float* xs     = z + (size_t)ROWS_ * DI_;       // 16777216
    float* xm     = xs + (size_t)ROWS_ * DI_;      // 8192
    float* xp     = xm + ROWS_;                    // 786432
    float* dec    = xp + (size_t)ROWS_ * 96;       // 8192
    float* u      = dec + ROWS_;                   // 8192
    float* S      = u + ROWS_;                     // 8192
    float* v16    = S + ROWS_;                     // 131072

    k1_gemm_in<<<dim3(ROWS_ / 64, NXZ_ / 64), 256, 0, stream>>>(x, Win, xs_raw, z);
    k2_conv<<<ROWS_, 256, 0, stream>>>(xs_raw, Wcv, xs, xm);
    k3_xproj<<<ROWS_ / 64, 256, 0, stream>>>(xs, Wxp, xp);
    k4_dt<<<ROWS_ / 32, 256, 0, stream>>>(xp, Wdt, bdt, xm, dec, u);
    k5_scan<<<1, 256, 0, stream>>>(dec, u, S);
    k6_v16<<<ROWS_ / 256, 256, 0, stream>>>(xp, S, v16);
    k7_out<<<dim3(ROWS_ / 64, D_ / 64), 256, 0, stream>>>(z, v16, lng, lnb, Wout, out);
}

// Round 3
// 543.379 us; speedup vs baseline: 3.6559x; 3.6559x over previous
//
#include <hip/hip_runtime.h>
#include <hip/hip_bf16.h>
#include <math.h>
#include <stdint.h>

#define D_    1024
#define DI_   2048
#define DS_   16
#define DTR_  64
#define B_    2
#define L_    4096
#define ROWS_ 8192
#define NXZ_  4096

typedef __attribute__((ext_vector_type(8))) __bf16 bf16x8;
typedef __attribute__((ext_vector_type(4))) float  f32x4;

__device__ __forceinline__ unsigned short f2bf(float f) {
    unsigned u = __float_as_uint(f);
    unsigned r = (u + 0x7fffu + ((u >> 16) & 1u)) >> 16;   // RNE
    return (unsigned short)r;
}
__device__ __forceinline__ float bf2f(unsigned short h) {
    return __uint_as_float(((unsigned)h) << 16);
}

// CK-style direct global->LDS 16B load (dest = wave-uniform base + lane*16)
__device__ __forceinline__ void gload16(const void* gp, void* lp) {
    auto* g1 = (const __attribute__((address_space(1))) unsigned int*)(uintptr_t)gp;
    auto* l3 = (__attribute__((address_space(3))) unsigned int*)(uintptr_t)lp;
    __builtin_amdgcn_global_load_lds(g1, l3, 16, 0, 0);
}

// ---------------------------------------------------------------------------
// cvt: fp32 -> bf16, same layout (for x)
// ---------------------------------------------------------------------------
__global__ __launch_bounds__(256) void kcvt(const float* __restrict__ in,
                                            unsigned short* __restrict__ out) {
    const int i = blockIdx.x * 256 + threadIdx.x;   // float4 index
    const float4 v = ((const float4*)in)[i];
    ushort4 o;
    o.x = f2bf(v.x); o.y = f2bf(v.y); o.z = f2bf(v.z); o.w = f2bf(v.w);
    ((ushort4*)out)[i] = o;
}

// ---------------------------------------------------------------------------
// transpose + cvt: W [R][C] f32 -> WT [C][R] bf16
// ---------------------------------------------------------------------------
__global__ __launch_bounds__(256) void ktrans(const float* __restrict__ W,
                                              unsigned short* __restrict__ WT,
                                              int R, int C) {
    __shared__ float tile[32][33];
    const int c0 = blockIdx.x * 32, r0 = blockIdx.y * 32;
    const int tc = threadIdx.x & 31, tr = threadIdx.x >> 5;   // tr: 0..7
#pragma unroll
    for (int i = 0; i < 32; i += 8)
        tile[tr + i][tc] = W[(size_t)(r0 + tr + i) * C + c0 + tc];
    __syncthreads();
#pragma unroll
    for (int i = 0; i < 32; i += 8)
        WT[(size_t)(c0 + tr + i) * R + r0 + tc] = f2bf(tile[tc][tr + i]);
}

// ---------------------------------------------------------------------------
// bf16 MFMA GEMM, 128x128 tile, BK=64, 4 waves, m97-style 2-barrier loop.
// A [M][K] bf16 row-major, B [N][K] bf16 row-major (i.e. B^T of math matrix).
// If nb < NB_SPLIT: write f32 to Cf (ldc cols); else write bf16 to Cz
// (2048 cols, col-2048).  (k1: NB_SPLIT=16 -> xs_raw / zbf; k7: all f32.)
// ---------------------------------------------------------------------------
template <int K, int NB_SPLIT>
__global__ __launch_bounds__(256, 2) void gemm_bf16(const unsigned short* __restrict__ A,
                                                    const unsigned short* __restrict__ B,
                                                    float* __restrict__ Cf, int ldc,
                                                    unsigned short* __restrict__ Cz) {
    const int t    = threadIdx.x;
    const int wid  = t >> 6, lane = t & 63;
    const int m0   = blockIdx.x * 128;
    const int nb   = blockIdx.y;
    const int n0   = nb * 128;
    const int wr   = wid >> 1, wc = wid & 1;
    __shared__ unsigned short Als[128 * 64];
    __shared__ unsigned short Bls[128 * 64];

    f32x4 acc[4][4];
    const f32x4 z4 = {0.f, 0.f, 0.f, 0.f};
#pragma unroll
    for (int m = 0; m < 4; ++m)
#pragma unroll
        for (int n = 0; n < 4; ++n) acc[m][n] = z4;

    int rowA[4], eoff[4];
#pragma unroll
    for (int i = 0; i < 4; ++i) {
        const int c = wid * 256 + i * 64 + lane;   // chunk 0..1023 (16B each)
        rowA[i] = c >> 3;                          // 8 chunks per 128B row
        eoff[i] = (c & 7) * 8;                     // bf16 elem offset in row
    }

    const int ar = wr * 64 + (lane & 15);
    const int br = wc * 64 + (lane & 15);
    const int kq = (lane >> 4) * 8;

    for (int k0 = 0; k0 < K; k0 += 64) {
#pragma unroll
        for (int i = 0; i < 4; ++i) {
            const int dst = (wid * 4 + i) * 1024;  // LDS byte offset, wave-uniform
            gload16(A + (size_t)(m0 + rowA[i]) * K + k0 + eoff[i], (char*)Als + dst);
            gload16(B + (size_t)(n0 + rowA[i]) * K + k0 + eoff[i], (char*)Bls + dst);
        }
        __syncthreads();
        bf16x8 af[4][2], bfr[4][2];
#pragma unroll
        for (int m = 0; m < 4; ++m)
#pragma unroll
            for (int kk = 0; kk < 2; ++kk)
                af[m][kk] = *(const bf16x8*)&Als[(ar + m * 16) * 64 + kk * 32 + kq];
#pragma unroll
        for (int n = 0; n < 4; ++n)
#pragma unroll
            for (int kk = 0; kk < 2; ++kk)
                bfr[n][kk] = *(const bf16x8*)&Bls[(br + n * 16) * 64 + kk * 32 + kq];
#pragma unroll
        for (int m = 0; m < 4; ++m)
#pragma unroll
            for (int n = 0; n < 4; ++n)
#pragma unroll
                for (int kk = 0; kk < 2; ++kk)
                    acc[m][n] = __builtin_amdgcn_mfma_f32_16x16x32_bf16(
                        af[m][kk], bfr[n][kk], acc[m][n], 0, 0, 0);
        __syncthreads();
    }

    const int crow = (lane >> 4) * 4, ccol = lane & 15;
    if (nb < NB_SPLIT) {
#pragma unroll
        for (int m = 0; m < 4; ++m)
#pragma unroll
            for (int n = 0; n < 4; ++n)
#pragma unroll
                for (int j = 0; j < 4; ++j)
                    Cf[(size_t)(m0 + wr * 64 + m * 16 + crow + j) * ldc +
                       (n0 + wc * 64 + n * 16 + ccol)] = acc[m][n][j];
    } else {
#pragma unroll
        for (int m = 0; m < 4; ++m)
#pragma unroll
            for (int n = 0; n < 4; ++n)
#pragma unroll
                for (int j = 0; j < 4; ++j)
                    Cz[(size_t)(m0 + wr * 64 + m * 16 + crow + j) * 2048 +
                       (n0 - 2048 + wc * 64 + n * 16 + ccol)] = f2bf(acc[m][n][j]);
    }
}

// ---------------------------------------------------------------------------
// k2: depthwise conv(k=3, same) along L + silu + row mean (xm). 1 block/row.
// ---------------------------------------------------------------------------
__global__ __launch_bounds__(256) void k2_conv(const float* __restrict__ xs_raw,
                                               const float* __restrict__ Wcv,
                                               float* __restrict__ xs,
                                               float* __restrict__ xm) {
    const int row = blockIdx.x;
    const int l   = row & (L_ - 1);
    const int t   = threadIdx.x;
    const float* cur = xs_raw + (size_t)row * DI_;
    const bool hasP = (l > 0), hasN = (l < L_ - 1);
    float lsum = 0.f;
    for (int c = t; c < DI_; c += 256) {
        const float w0 = Wcv[c * 3 + 0], w1 = Wcv[c * 3 + 1], w2 = Wcv[c * 3 + 2];
        float v = cur[c] * w1;
        if (hasP) v += cur[c - DI_] * w0;
        if (hasN) v += cur[c + DI_] * w2;
        const float s = v / (1.f + expf(-v));
        xs[(size_t)row * DI_ + c] = s;
        lsum += s;
    }
    __shared__ float red[256];
    red[t] = lsum;
    __syncthreads();
    for (int s = 128; s > 0; s >>= 1) {
        if (t < s) red[t] += red[t + s];
        __syncthreads();
    }
    if (t == 0) xm[row] = red[0] * (1.f / (float)DI_);
}

// ---------------------------------------------------------------------------
// k3: xp = xs @ W_xproj  (M=8192, K=2048, N=96). 64x48 tile, grid (128,2).
// ---------------------------------------------------------------------------
__global__ __launch_bounds__(256) void k3_xproj(const float* __restrict__ xs,
                                                const float* __restrict__ Wxp,
                                                float* __restrict__ xp) {
    const int t  = threadIdx.x;
    const int m0 = blockIdx.x * 64;
    const int n0 = blockIdx.y * 48;
    __shared__ float As[32][68];
    __shared__ float Bs[32][48];
    float acc[4][3] = {};
    const int tm = (t >> 4) * 4;
    const int tn = (t & 15) * 3;
    for (int k0 = 0; k0 < DI_; k0 += 32) {
#pragma unroll
        for (int i = 0; i < 2; ++i) {
            const int f = t + 256 * i;
            const int am = f >> 3, av = f & 7;
            const float4 v = *(const float4*)(xs + (size_t)(m0 + am) * DI_ + k0 + av * 4);
            As[av * 4 + 0][am] = v.x; As[av * 4 + 1][am] = v.y;
            As[av * 4 + 2][am] = v.z; As[av * 4 + 3][am] = v.w;
        }
#pragma unroll
        for (int i = 0; i < 6; ++i) {   // 32x48 = 1536
            const int e = t + 256 * i;
            const int bk = e / 48, bn = e - bk * 48;
            Bs[bk][bn] = Wxp[(size_t)(k0 + bk) * 96 + n0 + bn];
        }
        __syncthreads();
#pragma unroll
        for (int k = 0; k < 32; ++k) {
            float a[4], b[3];
#pragma unroll
            for (int i = 0; i < 4; ++i) a[i] = As[k][tm + i];
#pragma unroll
            for (int j = 0; j < 3; ++j) b[j] = Bs[k][tn + j];
#pragma unroll
            for (int i = 0; i < 4; ++i)
#pragma unroll
                for (int j = 0; j < 3; ++j) acc[i][j] += a[i] * b[j];
        }
        __syncthreads();
    }
#pragma unroll
    for (int i = 0; i < 4; ++i)
#pragma unroll
        for (int j = 0; j < 3; ++j)
            xp[(size_t)(m0 + tm + i) * 96 + n0 + tn + j] = acc[i][j];
}

// ---------------------------------------------------------------------------
// k4: dtm = mean_i softplus(dt_lo @ W_dt + b_dt); dec = exp(-dtm);
//     u = xm * sum(Bp).  16 rows/block (512 blocks).
// ---------------------------------------------------------------------------
__global__ __launch_bounds__(256) void k4_dt(const float* __restrict__ xp,
                                             const float* __restrict__ Wdt,
                                             const float* __restrict__ bdt,
                                             const float* __restrict__ xm,
                                             float* __restrict__ dec,
                                             float* __restrict__ u) {
    const int r0 = blockIdx.x * 16;
    const int t  = threadIdx.x;
    __shared__ float dlo[16][64];
    __shared__ float Wc[64][65];
    __shared__ float red[16][64];
#pragma unroll
    for (int i = 0; i < 4; ++i) {
        const int e = t + 256 * i;
        const int r = e >> 6, k = e & 63;
        dlo[r][k] = xp[(size_t)(r0 + r) * 96 + k];
    }
    float acc[4] = {};
    const int i_l   = t & 63;
    const int rbase = t >> 6;
    for (int i0 = 0; i0 < DI_; i0 += 64) {
        __syncthreads();
#pragma unroll
        for (int ii = 0; ii < 16; ++ii) {
            const int e = t + 256 * ii;
            const int wk = e >> 6, wi = e & 63;
            Wc[wk][wi] = Wdt[(size_t)wk * DI_ + i0 + wi];
        }
        __syncthreads();
        const float bb2 = bdt[i0 + i_l];
#pragma unroll
        for (int j = 0; j < 4; ++j) {
            const int r = rbase + 4 * j;
            float w = bb2;
#pragma unroll
            for (int k = 0; k < 64; ++k) w += dlo[r][k] * Wc[k][i_l];
            acc[j] += fmaxf(w, 0.f) + log1pf(expf(-fabsf(w)));
        }
    }
    __syncthreads();
#pragma unroll
    for (int j = 0; j < 4; ++j) red[rbase + 4 * j][i_l] = acc[j];
    __syncthreads();
    if (t < 16) {
        float tot = 0.f;
        for (int i = 0; i < 64; ++i) tot += red[t][i];
        const float dtm = tot * (1.f / (float)DI_);
        float sBp = 0.f;
        for (int s = 0; s < DS_; ++s) sBp += xp[(size_t)(r0 + t) * 96 + DTR_ + s];
        dec[r0 + t] = expf(-dtm);
        u[r0 + t]   = xm[r0 + t] * sBp;
    }
}

// ---------------------------------------------------------------------------
// k5: exact chunked scalar scan  S_l = d_l * S_{l-1} + u_l  (per batch).
// ---------------------------------------------------------------------------
__global__ __launch_bounds__(256) void k5_scan(const float* __restrict__ dec,
                                               const float* __restrict__ u,
                                               float* __restrict__ S) {
    const int t = threadIdx.x;
    __shared__ float aa[256], hh[256], init[256];
    const int b = t >> 7, c = t & 127;
    const int base = b * L_ + c * 32;
    float a = 1.f, h = 0.f;
    for (int i = 0; i < 32; ++i) {
        const float d = dec[base + i];
        h = h * d + u[base + i];
        a *= d;
    }
    aa[t] = a; hh[t] = h;
    __syncthreads();
    if (t < B_) {
        float run = 0.f;
        for (int cc = 0; cc < 128; ++cc) {
            const int tt = t * 128 + cc;
            init[tt] = run;
            run = hh[tt] + aa[tt] * run;
        }
    }
    __syncthreads();
    h = init[t];
    for (int i = 0; i < 32; ++i) {
        h = h * dec[base + i] + u[base + i];
        S[base + i] = h;
    }
}

// ---------------------------------------------------------------------------
// k6: per-row 16-vector v = Cp*S, LN stats over 16 (== LN over 2048 tile).
// ---------------------------------------------------------------------------
__global__ __launch_bounds__(256) void k6_v16(const float* __restrict__ xp,
                                              const float* __restrict__ S,
                                              float* __restrict__ v16) {
    const int row = blockIdx.x * 256 + threadIdx.x;
    const float s = S[row];
    float v[16], mu = 0.f;
#pragma unroll
    for (int i = 0; i < 16; ++i) {
        v[i] = xp[(size_t)row * 96 + DTR_ + DS_ + i] * s;
        mu += v[i];
    }
    mu *= (1.f / 16.f);
    float var = 0.f;
#pragma unroll
    for (int i = 0; i < 16; ++i) {
        const float d = v[i] - mu;
        var += d * d;
    }
    var *= (1.f / 16.f);
    const float rs = rsqrtf(var + 1e-5f);
#pragma unroll
    for (int i = 0; i < 16; ++i) v16[(size_t)row * 16 + i] = (v[i] - mu) * rs;
}

// ---------------------------------------------------------------------------
// kA7: Abf[row][i] = (v16[row][i&15]*g[i] + b[i]) * silu(z[row][i]), bf16.
// ---------------------------------------------------------------------------
__global__ __launch_bounds__(256) void kA7(const unsigned short* __restrict__ zbf,
                                           const float* __restrict__ v16,
                                           const float* __restrict__ g,
                                           const float* __restrict__ bb,
                                           unsigned short* __restrict__ Abf) {
    const int row = blockIdx.x;
    const int t   = threadIdx.x;
    __shared__ float vrow[16];
    if (t < 16) vrow[t] = v16[row * 16 + t];
    __syncthreads();
    const int i0 = t * 8;
    const uint4 zraw = *(const uint4*)(zbf + (size_t)row * DI_ + i0);
    const unsigned short* zp = (const unsigned short*)&zraw;
    const float4 g0 = *(const float4*)(g + i0),  g1 = *(const float4*)(g + i0 + 4);
    const float4 b0 = *(const float4*)(bb + i0), b1 = *(const float4*)(bb + i0 + 4);
    const float gv[8] = {g0.x, g0.y, g0.z, g0.w, g1.x, g1.y, g1.z, g1.w};
    const float bv[8] = {b0.x, b0.y, b0.z, b0.w, b1.x, b1.y, b1.z, b1.w};
    unsigned short o[8];
#pragma unroll
    for (int j = 0; j < 8; ++j) {
        const int i = i0 + j;
        const float zf = bf2f(zp[j]);
        const float sz = zf / (1.f + expf(-zf));
        o[j] = f2bf((vrow[i & 15] * gv[j] + bv[j]) * sz);
    }
    *(uint4*)(Abf + (size_t)row * DI_ + i0) = *(const uint4*)o;
}

// ---------------------------------------------------------------------------
extern "C" void kernel_launch(void* const* d_in, const int* in_sizes, int n_in,
                              void* d_out, int out_size, void* d_ws, size_t ws_size,
                              hipStream_t stream) {
    const float* x    = (const float*)d_in[0];
    const float* Win  = (const float*)d_in[1];
    const float* Wcv  = (const float*)d_in[2];
    const float* Wxp  = (const float*)d_in[3];
    const float* Wdt  = (const float*)d_in[4];
    const float* bdt  = (const float*)d_in[5];
    const float* Wout = (const float*)d_in[6];
    const float* lng  = (const float*)d_in[7];
    const float* lnb  = (const float*)d_in[8];
    float* out = (float*)d_out;

    // ---- workspace layout (bytes), ~197 MB total, with lifetime aliasing ----
    char* base = (char*)d_ws;
    float*          xs_raw = (float*)(base + 0);                    // 67.1 MB (k1->k2)
    unsigned short* Abf    = (unsigned short*)(base + 0);           // alias, after k2
    unsigned short* zbf    = (unsigned short*)(base + 67108864);    // 33.5 MB
    float*          xs     = (float*)(base + 100663296);            // 67.1 MB
    float*          xp     = (float*)(base + 167772160);            // 3.1 MB
    float*          xm     = (float*)(base + 170917888);
    float*          dec    = (float*)(base + 170950656);
    float*          u      = (float*)(base + 170983424);
    float*          S      = (float*)(base + 171016192);
    float*          v16    = (float*)(base + 171048960);            // 0.5 MB
    unsigned short* xbf    = (unsigned short*)(base + 171573248);   // 16.8 MB (dead after k1)
    unsigned short* WoutT  = (unsigned short*)(base + 171573248);   // alias, after k1
    unsigned short* WinT   = (unsigned short*)(base + 188350464);   // 8.4 MB

    kcvt<<<ROWS_ * D_ / 1024, 256, 0, stream>>>(x, xbf);
    ktrans<<<dim3(NXZ_ / 32, D_ / 32), 256, 0, stream>>>(Win, WinT, D_, NXZ_);
    gemm_bf16<D_, 16><<<dim3(ROWS_ / 128, NXZ_ / 128), 256, 0, stream>>>(
        xbf, WinT, xs_raw, DI_, zbf);
    ktrans<<<dim3(D_ / 32, DI_ / 32), 256, 0, stream>>>(Wout, WoutT, DI_, D_);
    k2_conv<<<ROWS_, 256, 0, stream>>>(xs_raw, Wcv, xs, xm);
    k3_xproj<<<dim3(ROWS_ / 64, 2), 256, 0, stream>>>(xs, Wxp, xp);
    k4_dt<<<ROWS_ / 16, 256, 0, stream>>>(xp, Wdt, bdt, xm, dec, u);
    k5_scan<<<1, 256, 0, stream>>>(dec, u, S);
    k6_v16<<<ROWS_ / 256, 256, 0, stream>>>(xp, S, v16);
    kA7<<<ROWS_, 256, 0, stream>>>(zbf, v16, lng, lnb, Abf);
    gemm_bf16<DI_, 8><<<dim3(ROWS_ / 128, D_ / 128), 256, 0, stream>>>(
        Abf, WoutT, out, D_, (unsigned short*)nullptr);
}

// Round 4
// 449.342 us; speedup vs baseline: 4.4210x; 1.2093x over previous
//
#include <hip/hip_runtime.h>
#include <hip/hip_bf16.h>
#include <math.h>
#include <stdint.h>

#define D_    1024
#define DI_   2048
#define DS_   16
#define DTR_  64
#define B_    2
#define L_    4096
#define ROWS_ 8192
#define NXZ_  4096

typedef __attribute__((ext_vector_type(8))) __bf16 bf16x8;
typedef __attribute__((ext_vector_type(4))) float  f32x4;

__device__ __forceinline__ unsigned short f2bf(float f) {
    unsigned u = __float_as_uint(f);
    unsigned r = (u + 0x7fffu + ((u >> 16) & 1u)) >> 16;   // RNE
    return (unsigned short)r;
}
__device__ __forceinline__ float bf2f(unsigned short h) {
    return __uint_as_float(((unsigned)h) << 16);
}

// direct global->LDS 16B load (dest = wave-uniform base + lane*16)
__device__ __forceinline__ void gload16(const void* gp, void* lp) {
    auto* g1 = (const __attribute__((address_space(1))) unsigned int*)(uintptr_t)gp;
    auto* l3 = (__attribute__((address_space(3))) unsigned int*)(uintptr_t)lp;
    __builtin_amdgcn_global_load_lds(g1, l3, 16, 0, 0);
}

// ---------------------------------------------------------------------------
// cvt: fp32 -> bf16, same layout (for x)
// ---------------------------------------------------------------------------
__global__ __launch_bounds__(256) void kcvt(const float* __restrict__ in,
                                            unsigned short* __restrict__ out) {
    const int i = blockIdx.x * 256 + threadIdx.x;   // float4 index
    const float4 v = ((const float4*)in)[i];
    ushort4 o;
    o.x = f2bf(v.x); o.y = f2bf(v.y); o.z = f2bf(v.z); o.w = f2bf(v.w);
    ((ushort4*)out)[i] = o;
}

// ---------------------------------------------------------------------------
// transpose + cvt + col-pad: W [R][Csrc] f32 -> WT [gridDim.x*32][R] bf16,
// rows >= Csrc zero-filled.
// ---------------------------------------------------------------------------
__global__ __launch_bounds__(256) void ktrans(const float* __restrict__ W,
                                              unsigned short* __restrict__ WT,
                                              int R, int Csrc) {
    __shared__ float tile[32][33];
    const int c0 = blockIdx.x * 32, r0 = blockIdx.y * 32;
    const int tc = threadIdx.x & 31, tr = threadIdx.x >> 5;   // tr: 0..7
#pragma unroll
    for (int i = 0; i < 32; i += 8)
        tile[tr + i][tc] = (c0 + tc < Csrc)
                           ? W[(size_t)(r0 + tr + i) * Csrc + c0 + tc] : 0.f;
    __syncthreads();
#pragma unroll
    for (int i = 0; i < 32; i += 8)
        WT[(size_t)(c0 + tr + i) * R + r0 + tc] = f2bf(tile[tc][tr + i]);
}

// ---------------------------------------------------------------------------
// bf16 MFMA GEMM, 128x128 tile, BK=64, 4 waves, 2-barrier loop + XCD swizzle.
// A [M][K] bf16 row-major, B [N][K] bf16 row-major (B^T of math matrix).
// Logical n-tile < NB_SPLIT: f32 -> Cf (ldc cols); else bf16 -> Cz (2048 cols).
// ---------------------------------------------------------------------------
template <int K, int NB_SPLIT>
__global__ __launch_bounds__(256, 2) void gemm_bf16(const unsigned short* __restrict__ A,
                                                    const unsigned short* __restrict__ B,
                                                    float* __restrict__ Cf, int ldc,
                                                    unsigned short* __restrict__ Cz) {
    const int t    = threadIdx.x;
    const int wid  = t >> 6, lane = t & 63;
    // XCD-aware bijective swizzle (nwg % 8 == 0 for all our grids)
    const int gx  = gridDim.x;
    const int nwg = gx * gridDim.y;
    int lin = blockIdx.y * gx + blockIdx.x;
    lin = (lin & 7) * (nwg >> 3) + (lin >> 3);
    const int bx = lin % gx;
    const int nb = lin / gx;
    const int m0 = bx * 128;
    const int n0 = nb * 128;
    const int wr = wid >> 1, wc = wid & 1;
    __shared__ unsigned short Als[128 * 64];
    __shared__ unsigned short Bls[128 * 64];

    f32x4 acc[4][4];
    const f32x4 z4 = {0.f, 0.f, 0.f, 0.f};
#pragma unroll
    for (int m = 0; m < 4; ++m)
#pragma unroll
        for (int n = 0; n < 4; ++n) acc[m][n] = z4;

    int rowA[4], eoff[4];
#pragma unroll
    for (int i = 0; i < 4; ++i) {
        const int c = wid * 256 + i * 64 + lane;   // chunk 0..1023 (16B each)
        rowA[i] = c >> 3;
        eoff[i] = (c & 7) * 8;
    }

    const int ar = wr * 64 + (lane & 15);
    const int br = wc * 64 + (lane & 15);
    const int kq = (lane >> 4) * 8;

    for (int k0 = 0; k0 < K; k0 += 64) {
#pragma unroll
        for (int i = 0; i < 4; ++i) {
            const int dst = (wid * 4 + i) * 1024;
            gload16(A + (size_t)(m0 + rowA[i]) * K + k0 + eoff[i], (char*)Als + dst);
            gload16(B + (size_t)(n0 + rowA[i]) * K + k0 + eoff[i], (char*)Bls + dst);
        }
        __syncthreads();
        bf16x8 af[4][2], bfr[4][2];
#pragma unroll
        for (int m = 0; m < 4; ++m)
#pragma unroll
            for (int kk = 0; kk < 2; ++kk)
                af[m][kk] = *(const bf16x8*)&Als[(ar + m * 16) * 64 + kk * 32 + kq];
#pragma unroll
        for (int n = 0; n < 4; ++n)
#pragma unroll
            for (int kk = 0; kk < 2; ++kk)
                bfr[n][kk] = *(const bf16x8*)&Bls[(br + n * 16) * 64 + kk * 32 + kq];
#pragma unroll
        for (int m = 0; m < 4; ++m)
#pragma unroll
            for (int n = 0; n < 4; ++n)
#pragma unroll
                for (int kk = 0; kk < 2; ++kk)
                    acc[m][n] = __builtin_amdgcn_mfma_f32_16x16x32_bf16(
                        af[m][kk], bfr[n][kk], acc[m][n], 0, 0, 0);
        __syncthreads();
    }

    const int crow = (lane >> 4) * 4, ccol = lane & 15;
    if (nb < NB_SPLIT) {
#pragma unroll
        for (int m = 0; m < 4; ++m)
#pragma unroll
            for (int n = 0; n < 4; ++n)
#pragma unroll
                for (int j = 0; j < 4; ++j)
                    Cf[(size_t)(m0 + wr * 64 + m * 16 + crow + j) * ldc +
                       (n0 + wc * 64 + n * 16 + ccol)] = acc[m][n][j];
    } else {
#pragma unroll
        for (int m = 0; m < 4; ++m)
#pragma unroll
            for (int n = 0; n < 4; ++n)
#pragma unroll
                for (int j = 0; j < 4; ++j)
                    Cz[(size_t)(m0 + wr * 64 + m * 16 + crow + j) * 2048 +
                       (n0 - 2048 + wc * 64 + n * 16 + ccol)] = f2bf(acc[m][n][j]);
    }
}

// ---------------------------------------------------------------------------
// k2: depthwise conv(k=3) + silu -> bf16 xsb, + fp32 row mean (xm).
// 16 rows/block, thread owns 8 consecutive channels.
// ---------------------------------------------------------------------------
__global__ __launch_bounds__(256) void k2_conv(const float* __restrict__ xs_raw,
                                               const float* __restrict__ Wcv,
                                               unsigned short* __restrict__ xsb,
                                               float* __restrict__ xm) {
    const int t = threadIdx.x;
    const int wid = t >> 6, lane = t & 63;
    const int row0 = blockIdx.x * 16;
    const int c0 = t * 8;
    __shared__ float wsum[16][4];
    float w0[8], w1[8], w2[8];
#pragma unroll
    for (int j = 0; j < 8; ++j) {
        w0[j] = Wcv[(c0 + j) * 3 + 0];
        w1[j] = Wcv[(c0 + j) * 3 + 1];
        w2[j] = Wcv[(c0 + j) * 3 + 2];
    }
    for (int r = 0; r < 16; ++r) {
        const int row = row0 + r;
        const int l = row & (L_ - 1);
        const float* cur = xs_raw + (size_t)row * DI_ + c0;
        float cv[8], pv[8] = {}, nv[8] = {};
        {
            const float4 a = *(const float4*)cur, b = *(const float4*)(cur + 4);
            cv[0]=a.x; cv[1]=a.y; cv[2]=a.z; cv[3]=a.w;
            cv[4]=b.x; cv[5]=b.y; cv[6]=b.z; cv[7]=b.w;
        }
        if (l > 0) {
            const float4 a = *(const float4*)(cur - DI_), b = *(const float4*)(cur - DI_ + 4);
            pv[0]=a.x; pv[1]=a.y; pv[2]=a.z; pv[3]=a.w;
            pv[4]=b.x; pv[5]=b.y; pv[6]=b.z; pv[7]=b.w;
        }
        if (l < L_ - 1) {
            const float4 a = *(const float4*)(cur + DI_), b = *(const float4*)(cur + DI_ + 4);
            nv[0]=a.x; nv[1]=a.y; nv[2]=a.z; nv[3]=a.w;
            nv[4]=b.x; nv[5]=b.y; nv[6]=b.z; nv[7]=b.w;
        }
        float s8 = 0.f;
        unsigned short o[8];
#pragma unroll
        for (int j = 0; j < 8; ++j) {
            const float v = cv[j] * w1[j] + pv[j] * w0[j] + nv[j] * w2[j];
            const float s = v / (1.f + expf(-v));
            o[j] = f2bf(s);
            s8 += s;
        }
        *(uint4*)(xsb + (size_t)row * DI_ + c0) = *(const uint4*)o;
#pragma unroll
        for (int k = 1; k < 64; k <<= 1) s8 += __shfl_xor(s8, k);
        if (lane == 0) wsum[r][wid] = s8;
    }
    __syncthreads();
    if (t < 16)
        xm[row0 + t] = (wsum[t][0] + wsum[t][1] + wsum[t][2] + wsum[t][3]) * (1.f / (float)DI_);
}

// ---------------------------------------------------------------------------
// k3m: split-K bf16 MFMA GEMM  xp_part[kc] += xsb @ WxpT^T.
// M=8192 (128/blk), N=128 (96 valid), K-chunk = 512. grid (64, 4).
// ---------------------------------------------------------------------------
__global__ __launch_bounds__(256, 2) void k3m(const unsigned short* __restrict__ A,
                                              const unsigned short* __restrict__ B,
                                              float* __restrict__ part) {
    const int t = threadIdx.x;
    const int wid = t >> 6, lane = t & 63;
    const int m0 = blockIdx.x * 128;
    const int kc = blockIdx.y;
    const int wr = wid >> 1, wc = wid & 1;
    __shared__ unsigned short Als[128 * 64];
    __shared__ unsigned short Bls[128 * 64];
    f32x4 acc[4][4];
    const f32x4 z4 = {0.f, 0.f, 0.f, 0.f};
#pragma unroll
    for (int m = 0; m < 4; ++m)
#pragma unroll
        for (int n = 0; n < 4; ++n) acc[m][n] = z4;
    int rowA[4], eoff[4];
#pragma unroll
    for (int i = 0; i < 4; ++i) {
        const int c = wid * 256 + i * 64 + lane;
        rowA[i] = c >> 3;
        eoff[i] = (c & 7) * 8;
    }
    const int ar = wr * 64 + (lane & 15);
    const int br = wc * 64 + (lane & 15);
    const int kq = (lane >> 4) * 8;
    const int kbase = kc * 512;
    for (int k0 = kbase; k0 < kbase + 512; k0 += 64) {
#pragma unroll
        for (int i = 0; i < 4; ++i) {
            const int dst = (wid * 4 + i) * 1024;
            gload16(A + (size_t)(m0 + rowA[i]) * DI_ + k0 + eoff[i], (char*)Als + dst);
            gload16(B + (size_t)rowA[i] * DI_ + k0 + eoff[i], (char*)Bls + dst);
        }
        __syncthreads();
        bf16x8 af[4][2], bfr[4][2];
#pragma unroll
        for (int m = 0; m < 4; ++m)
#pragma unroll
            for (int kk = 0; kk < 2; ++kk)
                af[m][kk] = *(const bf16x8*)&Als[(ar + m * 16) * 64 + kk * 32 + kq];
#pragma unroll
        for (int n = 0; n < 4; ++n)
#pragma unroll
            for (int kk = 0; kk < 2; ++kk)
                bfr[n][kk] = *(const bf16x8*)&Bls[(br + n * 16) * 64 + kk * 32 + kq];
#pragma unroll
        for (int m = 0; m < 4; ++m)
#pragma unroll
            for (int n = 0; n < 4; ++n)
#pragma unroll
                for (int kk = 0; kk < 2; ++kk)
                    acc[m][n] = __builtin_amdgcn_mfma_f32_16x16x32_bf16(
                        af[m][kk], bfr[n][kk], acc[m][n], 0, 0, 0);
        __syncthreads();
    }
    const int crow = (lane >> 4) * 4, ccol = lane & 15;
#pragma unroll
    for (int m = 0; m < 4; ++m)
#pragma unroll
        for (int n = 0; n < 4; ++n) {
            const int col = wc * 64 + n * 16 + ccol;
            if (col < 96) {
#pragma unroll
                for (int j = 0; j < 4; ++j)
                    part[((size_t)kc * ROWS_ + m0 + wr * 64 + m * 16 + crow + j) * 96 + col] =
                        acc[m][n][j];
            }
        }
}

// ---------------------------------------------------------------------------
// kred: xp = sum over 4 split-K partials (float4 lanes).
// ---------------------------------------------------------------------------
__global__ __launch_bounds__(256) void kred(const float* __restrict__ part,
                                            float* __restrict__ xp) {
    const int i = blockIdx.x * 256 + threadIdx.x;            // float4 idx, 196608 total
    const size_t stride = (size_t)ROWS_ * 96 / 4;
    const float4* p = (const float4*)part;
    float4 a = p[i], b = p[i + stride], c = p[i + 2 * stride], d = p[i + 3 * stride];
    float4 o;
    o.x = a.x + b.x + c.x + d.x;
    o.y = a.y + b.y + c.y + d.y;
    o.z = a.z + b.z + c.z + d.z;
    o.w = a.w + b.w + c.w + d.w;
    ((float4*)xp)[i] = o;
}

// ---------------------------------------------------------------------------
// k4: dtm = mean_i softplus(dt_lo @ W_dt + b_dt); dec = exp(-dtm);
//     u = xm * sum(Bp).  16 rows/block (512 blocks).
// ---------------------------------------------------------------------------
__global__ __launch_bounds__(256) void k4_dt(const float* __restrict__ xp,
                                             const float* __restrict__ Wdt,
                                             const float* __restrict__ bdt,
                                             const float* __restrict__ xm,
                                             float* __restrict__ dec,
                                             float* __restrict__ u) {
    const int r0 = blockIdx.x * 16;
    const int t  = threadIdx.x;
    __shared__ float dlo[16][64];
    __shared__ float Wc[64][65];
    __shared__ float red[16][64];
#pragma unroll
    for (int i = 0; i < 4; ++i) {
        const int e = t + 256 * i;
        const int r = e >> 6, k = e & 63;
        dlo[r][k] = xp[(size_t)(r0 + r) * 96 + k];
    }
    float acc[4] = {};
    const int i_l   = t & 63;
    const int rbase = t >> 6;
    for (int i0 = 0; i0 < DI_; i0 += 64) {
        __syncthreads();
#pragma unroll
        for (int ii = 0; ii < 16; ++ii) {
            const int e = t + 256 * ii;
            const int wk = e >> 6, wi = e & 63;
            Wc[wk][wi] = Wdt[(size_t)wk * DI_ + i0 + wi];
        }
        __syncthreads();
        const float bb2 = bdt[i0 + i_l];
#pragma unroll
        for (int j = 0; j < 4; ++j) {
            const int r = rbase + 4 * j;
            float w = bb2;
#pragma unroll
            for (int k = 0; k < 64; ++k) w += dlo[r][k] * Wc[k][i_l];
            acc[j] += fmaxf(w, 0.f) + log1pf(expf(-fabsf(w)));
        }
    }
    __syncthreads();
#pragma unroll
    for (int j = 0; j < 4; ++j) red[rbase + 4 * j][i_l] = acc[j];
    __syncthreads();
    if (t < 16) {
        float tot = 0.f;
        for (int i = 0; i < 64; ++i) tot += red[t][i];
        const float dtm = tot * (1.f / (float)DI_);
        float sBp = 0.f;
        for (int s = 0; s < DS_; ++s) sBp += xp[(size_t)(r0 + t) * 96 + DTR_ + s];
        dec[r0 + t] = expf(-dtm);
        u[r0 + t]   = xm[r0 + t] * sBp;
    }
}

// ---------------------------------------------------------------------------
// k5: exact chunked scalar scan  S_l = d_l * S_{l-1} + u_l  (per batch).
// ---------------------------------------------------------------------------
__global__ __launch_bounds__(256) void k5_scan(const float* __restrict__ dec,
                                               const float* __restrict__ u,
                                               float* __restrict__ S) {
    const int t = threadIdx.x;
    __shared__ float aa[256], hh[256], init[256];
    const int b = t >> 7, c = t & 127;
    const int base = b * L_ + c * 32;
    float a = 1.f, h = 0.f;
    for (int i = 0; i < 32; ++i) {
        const float d = dec[base + i];
        h = h * d + u[base + i];
        a *= d;
    }
    aa[t] = a; hh[t] = h;
    __syncthreads();
    if (t < B_) {
        float run = 0.f;
        for (int cc = 0; cc < 128; ++cc) {
            const int tt = t * 128 + cc;
            init[tt] = run;
            run = hh[tt] + aa[tt] * run;
        }
    }
    __syncthreads();
    h = init[t];
    for (int i = 0; i < 32; ++i) {
        h = h * dec[base + i] + u[base + i];
        S[base + i] = h;
    }
}

// ---------------------------------------------------------------------------
// k6: per-row 16-vector v = Cp*S, LN stats over 16 (== LN over 2048 tile).
// ---------------------------------------------------------------------------
__global__ __launch_bounds__(256) void k6_v16(const float* __restrict__ xp,
                                              const float* __restrict__ S,
                                              float* __restrict__ v16) {
    const int row = blockIdx.x * 256 + threadIdx.x;
    const float s = S[row];
    float v[16], mu = 0.f;
#pragma unroll
    for (int i = 0; i < 16; ++i) {
        v[i] = xp[(size_t)row * 96 + DTR_ + DS_ + i] * s;
        mu += v[i];
    }
    mu *= (1.f / 16.f);
    float var = 0.f;
#pragma unroll
    for (int i = 0; i < 16; ++i) {
        const float d = v[i] - mu;
        var += d * d;
    }
    var *= (1.f / 16.f);
    const float rs = rsqrtf(var + 1e-5f);
#pragma unroll
    for (int i = 0; i < 16; ++i) v16[(size_t)row * 16 + i] = (v[i] - mu) * rs;
}

// ---------------------------------------------------------------------------
// kA7: Abf[row][i] = (v16[row][i&15]*g[i] + b[i]) * silu(z[row][i]), bf16.
// ---------------------------------------------------------------------------
__global__ __launch_bounds__(256) void kA7(const unsigned short* __restrict__ zbf,
                                           const float* __restrict__ v16,
                                           const float* __restrict__ g,
                                           const float* __restrict__ bb,
                                           unsigned short* __restrict__ Abf) {
    const int row = blockIdx.x;
    const int t   = threadIdx.x;
    __shared__ float vrow[16];
    if (t < 16) vrow[t] = v16[row * 16 + t];
    __syncthreads();
    const int i0 = t * 8;
    const uint4 zraw = *(const uint4*)(zbf + (size_t)row * DI_ + i0);
    const unsigned short* zp = (const unsigned short*)&zraw;
    const float4 g0 = *(const float4*)(g + i0),  g1 = *(const float4*)(g + i0 + 4);
    const float4 b0 = *(const float4*)(bb + i0), b1 = *(const float4*)(bb + i0 + 4);
    const float gv[8] = {g0.x, g0.y, g0.z, g0.w, g1.x, g1.y, g1.z, g1.w};
    const float bv[8] = {b0.x, b0.y, b0.z, b0.w, b1.x, b1.y, b1.z, b1.w};
    unsigned short o[8];
#pragma unroll
    for (int j = 0; j < 8; ++j) {
        const int i = i0 + j;
        const float zf = bf2f(zp[j]);
        const float sz = zf / (1.f + expf(-zf));
        o[j] = f2bf((vrow[i & 15] * gv[j] + bv[j]) * sz);
    }
    *(uint4*)(Abf + (size_t)row * DI_ + i0) = *(const uint4*)o;
}

// ---------------------------------------------------------------------------
extern "C" void kernel_launch(void* const* d_in, const int* in_sizes, int n_in,
                              void* d_out, int out_size, void* d_ws, size_t ws_size,
                              hipStream_t stream) {
    const float* x    = (const float*)d_in[0];
    const float* Win  = (const float*)d_in[1];
    const float* Wcv  = (const float*)d_in[2];
    const float* Wxp  = (const float*)d_in[3];
    const float* Wdt  = (const float*)d_in[4];
    const float* bdt  = (const float*)d_in[5];
    const float* Wout = (const float*)d_in[6];
    const float* lng  = (const float*)d_in[7];
    const float* lnb  = (const float*)d_in[8];
    float* out = (float*)d_out;

    // ---- workspace layout (bytes), ~176 MB, lifetime-aliased ----
    char* base = (char*)d_ws;
    float*          xs_raw  = (float*)(base + 0);                    // 67.1 MB (k1->k2)
    unsigned short* Abf     = (unsigned short*)(base + 0);           // alias, after k2
    unsigned short* zbf     = (unsigned short*)(base + 67108864);    // 33.5 MB
    unsigned short* xsb     = (unsigned short*)(base + 100663296);   // 33.5 MB bf16
    float*          xp_part = (float*)(base + 134217728);            // 12.6 MB
    float*          xp      = (float*)(base + 146800640);            // 3.1 MB
    float*          xm      = (float*)(base + 149946368);
    float*          dec     = (float*)(base + 149979136);
    float*          u       = (float*)(base + 150011904);
    float*          S       = (float*)(base + 150044672);
    float*          v16     = (float*)(base + 150077440);            // 0.5 MB
    unsigned short* xbf     = (unsigned short*)(base + 150601728);   // 16.8 MB (dead after k1)
    unsigned short* WoutT   = (unsigned short*)(base + 150601728);   // alias, after k1
    unsigned short* WinT    = (unsigned short*)(base + 167378944);   // 8.4 MB
    unsigned short* WxpT    = (unsigned short*)(base + 175767552);   // 0.5 MB [128][2048]

    kcvt<<<ROWS_ * D_ / 1024, 256, 0, stream>>>(x, xbf);
    ktrans<<<dim3(NXZ_ / 32, D_ / 32), 256, 0, stream>>>(Win, WinT, D_, NXZ_);
    ktrans<<<dim3(4, DI_ / 32), 256, 0, stream>>>(Wxp, WxpT, DI_, 96);
    gemm_bf16<D_, 16><<<dim3(ROWS_ / 128, NXZ_ / 128), 256, 0, stream>>>(
        xbf, WinT, xs_raw, DI_, zbf);
    ktrans<<<dim3(D_ / 32, DI_ / 32), 256, 0, stream>>>(Wout, WoutT, DI_, D_);
    k2_conv<<<ROWS_ / 16, 256, 0, stream>>>(xs_raw, Wcv, xsb, xm);
    k3m<<<dim3(ROWS_ / 128, 4), 256, 0, stream>>>(xsb, WxpT, xp_part);
    kred<<<ROWS_ * 96 / 4 / 256, 256, 0, stream>>>(xp_part, xp);
    k4_dt<<<ROWS_ / 16, 256, 0, stream>>>(xp, Wdt, bdt, xm, dec, u);
    k5_scan<<<1, 256, 0, stream>>>(dec, u, S);
    k6_v16<<<ROWS_ / 256, 256, 0, stream>>>(xp, S, v16);
    kA7<<<ROWS_, 256, 0, stream>>>(zbf, v16, lng, lnb, Abf);
    gemm_bf16<DI_, 8><<<dim3(ROWS_ / 128, D_ / 128), 256, 0, stream>>>(
        Abf, WoutT, out, D_, (unsigned short*)nullptr);
}

// Round 5
// 387.427 us; speedup vs baseline: 5.1275x; 1.1598x over previous
//
#include <hip/hip_runtime.h>
#include <hip/hip_bf16.h>
#include <math.h>
#include <stdint.h>

#define D_    1024
#define DI_   2048
#define DS_   16
#define DTR_  64
#define B_    2
#define L_    4096
#define ROWS_ 8192
#define NXZ_  4096

typedef __attribute__((ext_vector_type(8))) __bf16 bf16x8;
typedef __attribute__((ext_vector_type(4))) float  f32x4;

__device__ __forceinline__ unsigned short f2bf(float f) {
    unsigned u = __float_as_uint(f);
    unsigned r = (u + 0x7fffu + ((u >> 16) & 1u)) >> 16;   // RNE
    return (unsigned short)r;
}
__device__ __forceinline__ float bf2f(unsigned short h) {
    return __uint_as_float(((unsigned)h) << 16);
}

// direct global->LDS 16B load (dest = wave-uniform base + lane*16)
__device__ __forceinline__ void gload16(const void* gp, void* lp) {
    auto* g1 = (const __attribute__((address_space(1))) unsigned int*)(uintptr_t)gp;
    auto* l3 = (__attribute__((address_space(3))) unsigned int*)(uintptr_t)lp;
    __builtin_amdgcn_global_load_lds(g1, l3, 16, 0, 0);
}

// ---------------------------------------------------------------------------
// cvt: fp32 -> bf16, same layout (for x)
// ---------------------------------------------------------------------------
__global__ __launch_bounds__(256) void kcvt(const float* __restrict__ in,
                                            unsigned short* __restrict__ out) {
    const int i = blockIdx.x * 256 + threadIdx.x;   // float4 index
    const float4 v = ((const float4*)in)[i];
    ushort4 o;
    o.x = f2bf(v.x); o.y = f2bf(v.y); o.z = f2bf(v.z); o.w = f2bf(v.w);
    ((ushort4*)out)[i] = o;
}

// ---------------------------------------------------------------------------
// transpose + cvt + col-pad: W [R][Csrc] f32 -> WT [gridDim.x*32][R] bf16,
// rows >= Csrc zero-filled.
// ---------------------------------------------------------------------------
__global__ __launch_bounds__(256) void ktrans(const float* __restrict__ W,
                                              unsigned short* __restrict__ WT,
                                              int R, int Csrc) {
    __shared__ float tile[32][33];
    const int c0 = blockIdx.x * 32, r0 = blockIdx.y * 32;
    const int tc = threadIdx.x & 31, tr = threadIdx.x >> 5;   // tr: 0..7
#pragma unroll
    for (int i = 0; i < 32; i += 8)
        tile[tr + i][tc] = (c0 + tc < Csrc)
                           ? W[(size_t)(r0 + tr + i) * Csrc + c0 + tc] : 0.f;
    __syncthreads();
#pragma unroll
    for (int i = 0; i < 32; i += 8)
        WT[(size_t)(c0 + tr + i) * R + r0 + tc] = f2bf(tile[tc][tr + i]);
}

// ---------------------------------------------------------------------------
// bf16 MFMA GEMM, 128x128 tile, BK=64, 4 waves, 2-barrier loop + XCD swizzle.
// A [M][K] bf16 row-major, B [N][K] bf16 row-major (B^T of math matrix).
// BF16OUT: write bf16 to Cp (ldc cols), else f32.
// ---------------------------------------------------------------------------
template <int K, bool BF16OUT>
__global__ __launch_bounds__(256, 3) void gemm_bf16(const unsigned short* __restrict__ A,
                                                    const unsigned short* __restrict__ B,
                                                    void* __restrict__ Cp, int ldc) {
    const int t    = threadIdx.x;
    const int wid  = t >> 6, lane = t & 63;
    // XCD-aware bijective swizzle (nwg % 8 == 0 for all our grids)
    const int gx  = gridDim.x;
    const int nwg = gx * gridDim.y;
    int lin = blockIdx.y * gx + blockIdx.x;
    lin = (lin & 7) * (nwg >> 3) + (lin >> 3);
    const int bx = lin % gx;
    const int nb = lin / gx;
    const int m0 = bx * 128;
    const int n0 = nb * 128;
    const int wr = wid >> 1, wc = wid & 1;
    __shared__ unsigned short Als[128 * 64];
    __shared__ unsigned short Bls[128 * 64];

    f32x4 acc[4][4];
    const f32x4 z4 = {0.f, 0.f, 0.f, 0.f};
#pragma unroll
    for (int m = 0; m < 4; ++m)
#pragma unroll
        for (int n = 0; n < 4; ++n) acc[m][n] = z4;

    int rowA[4], eoff[4];
#pragma unroll
    for (int i = 0; i < 4; ++i) {
        const int c = wid * 256 + i * 64 + lane;   // chunk 0..1023 (16B each)
        rowA[i] = c >> 3;
        eoff[i] = (c & 7) * 8;
    }

    const int ar = wr * 64 + (lane & 15);
    const int br = wc * 64 + (lane & 15);
    const int kq = (lane >> 4) * 8;

    for (int k0 = 0; k0 < K; k0 += 64) {
#pragma unroll
        for (int i = 0; i < 4; ++i) {
            const int dst = (wid * 4 + i) * 1024;
            gload16(A + (size_t)(m0 + rowA[i]) * K + k0 + eoff[i], (char*)Als + dst);
            gload16(B + (size_t)(n0 + rowA[i]) * K + k0 + eoff[i], (char*)Bls + dst);
        }
        __syncthreads();
        bf16x8 af[4][2], bfr[4][2];
#pragma unroll
        for (int m = 0; m < 4; ++m)
#pragma unroll
            for (int kk = 0; kk < 2; ++kk)
                af[m][kk] = *(const bf16x8*)&Als[(ar + m * 16) * 64 + kk * 32 + kq];
#pragma unroll
        for (int n = 0; n < 4; ++n)
#pragma unroll
            for (int kk = 0; kk < 2; ++kk)
                bfr[n][kk] = *(const bf16x8*)&Bls[(br + n * 16) * 64 + kk * 32 + kq];
#pragma unroll
        for (int m = 0; m < 4; ++m)
#pragma unroll
            for (int n = 0; n < 4; ++n)
#pragma unroll
                for (int kk = 0; kk < 2; ++kk)
                    acc[m][n] = __builtin_amdgcn_mfma_f32_16x16x32_bf16(
                        af[m][kk], bfr[n][kk], acc[m][n], 0, 0, 0);
        __syncthreads();
    }

    const int crow = (lane >> 4) * 4, ccol = lane & 15;
#pragma unroll
    for (int m = 0; m < 4; ++m)
#pragma unroll
        for (int n = 0; n < 4; ++n)
#pragma unroll
            for (int j = 0; j < 4; ++j) {
                const size_t idx = (size_t)(m0 + wr * 64 + m * 16 + crow + j) * ldc +
                                   (n0 + wc * 64 + n * 16 + ccol);
                if (BF16OUT) ((unsigned short*)Cp)[idx] = f2bf(acc[m][n][j]);
                else         ((float*)Cp)[idx] = acc[m][n][j];
            }
}

// ---------------------------------------------------------------------------
// k2: depthwise conv(k=3) + silu -> bf16 xsb, + fp32 row mean (xm).
// Input: xz_bf [8192][4096] bf16, cols 0..2047. 16 rows/block.
// ---------------------------------------------------------------------------
__global__ __launch_bounds__(256) void k2_conv(const unsigned short* __restrict__ xz,
                                               const float* __restrict__ Wcv,
                                               unsigned short* __restrict__ xsb,
                                               float* __restrict__ xm) {
    const int t = threadIdx.x;
    const int wid = t >> 6, lane = t & 63;
    const int row0 = blockIdx.x * 16;
    const int c0 = t * 8;
    __shared__ float wsum[16][4];
    float w0[8], w1[8], w2[8];
#pragma unroll
    for (int j = 0; j < 8; ++j) {
        w0[j] = Wcv[(c0 + j) * 3 + 0];
        w1[j] = Wcv[(c0 + j) * 3 + 1];
        w2[j] = Wcv[(c0 + j) * 3 + 2];
    }
    for (int r = 0; r < 16; ++r) {
        const int row = row0 + r;
        const int l = row & (L_ - 1);
        const unsigned short* cur = xz + (size_t)row * NXZ_ + c0;
        float cv[8], pv[8] = {}, nv[8] = {};
        {
            const uint4 raw = *(const uint4*)cur;
            const unsigned short* p = (const unsigned short*)&raw;
#pragma unroll
            for (int j = 0; j < 8; ++j) cv[j] = bf2f(p[j]);
        }
        if (l > 0) {
            const uint4 raw = *(const uint4*)(cur - NXZ_);
            const unsigned short* p = (const unsigned short*)&raw;
#pragma unroll
            for (int j = 0; j < 8; ++j) pv[j] = bf2f(p[j]);
        }
        if (l < L_ - 1) {
            const uint4 raw = *(const uint4*)(cur + NXZ_);
            const unsigned short* p = (const unsigned short*)&raw;
#pragma unroll
            for (int j = 0; j < 8; ++j) nv[j] = bf2f(p[j]);
        }
        float s8 = 0.f;
        unsigned short o[8];
#pragma unroll
        for (int j = 0; j < 8; ++j) {
            const float v = cv[j] * w1[j] + pv[j] * w0[j] + nv[j] * w2[j];
            const float s = v / (1.f + expf(-v));
            o[j] = f2bf(s);
            s8 += s;
        }
        *(uint4*)(xsb + (size_t)row * DI_ + c0) = *(const uint4*)o;
#pragma unroll
        for (int k = 1; k < 64; k <<= 1) s8 += __shfl_xor(s8, k);
        if (lane == 0) wsum[r][wid] = s8;
    }
    __syncthreads();
    if (t < 16)
        xm[row0 + t] = (wsum[t][0] + wsum[t][1] + wsum[t][2] + wsum[t][3]) * (1.f / (float)DI_);
}

// ---------------------------------------------------------------------------
// k3m: split-K bf16 MFMA GEMM  xp_part[kc] = xsb @ WxpT^T (K-chunk 512).
// M=8192 (128/blk), N=128 (96 valid). grid (64, 4).
// ---------------------------------------------------------------------------
__global__ __launch_bounds__(256, 2) void k3m(const unsigned short* __restrict__ A,
                                              const unsigned short* __restrict__ B,
                                              float* __restrict__ part) {
    const int t = threadIdx.x;
    const int wid = t >> 6, lane = t & 63;
    const int m0 = blockIdx.x * 128;
    const int kc = blockIdx.y;
    const int wr = wid >> 1, wc = wid & 1;
    __shared__ unsigned short Als[128 * 64];
    __shared__ unsigned short Bls[128 * 64];
    f32x4 acc[4][4];
    const f32x4 z4 = {0.f, 0.f, 0.f, 0.f};
#pragma unroll
    for (int m = 0; m < 4; ++m)
#pragma unroll
        for (int n = 0; n < 4; ++n) acc[m][n] = z4;
    int rowA[4], eoff[4];
#pragma unroll
    for (int i = 0; i < 4; ++i) {
        const int c = wid * 256 + i * 64 + lane;
        rowA[i] = c >> 3;
        eoff[i] = (c & 7) * 8;
    }
    const int ar = wr * 64 + (lane & 15);
    const int br = wc * 64 + (lane & 15);
    const int kq = (lane >> 4) * 8;
    const int kbase = kc * 512;
    for (int k0 = kbase; k0 < kbase + 512; k0 += 64) {
#pragma unroll
        for (int i = 0; i < 4; ++i) {
            const int dst = (wid * 4 + i) * 1024;
            gload16(A + (size_t)(m0 + rowA[i]) * DI_ + k0 + eoff[i], (char*)Als + dst);
            gload16(B + (size_t)rowA[i] * DI_ + k0 + eoff[i], (char*)Bls + dst);
        }
        __syncthreads();
        bf16x8 af[4][2], bfr[4][2];
#pragma unroll
        for (int m = 0; m < 4; ++m)
#pragma unroll
            for (int kk = 0; kk < 2; ++kk)
                af[m][kk] = *(const bf16x8*)&Als[(ar + m * 16) * 64 + kk * 32 + kq];
#pragma unroll
        for (int n = 0; n < 4; ++n)
#pragma unroll
            for (int kk = 0; kk < 2; ++kk)
                bfr[n][kk] = *(const bf16x8*)&Bls[(br + n * 16) * 64 + kk * 32 + kq];
#pragma unroll
        for (int m = 0; m < 4; ++m)
#pragma unroll
            for (int n = 0; n < 4; ++n)
#pragma unroll
                for (int kk = 0; kk < 2; ++kk)
                    acc[m][n] = __builtin_amdgcn_mfma_f32_16x16x32_bf16(
                        af[m][kk], bfr[n][kk], acc[m][n], 0, 0, 0);
        __syncthreads();
    }
    const int crow = (lane >> 4) * 4, ccol = lane & 15;
#pragma unroll
    for (int m = 0; m < 4; ++m)
#pragma unroll
        for (int n = 0; n < 4; ++n) {
            const int col = wc * 64 + n * 16 + ccol;
            if (col < 96) {
#pragma unroll
                for (int j = 0; j < 4; ++j)
                    part[((size_t)kc * ROWS_ + m0 + wr * 64 + m * 16 + crow + j) * 96 + col] =
                        acc[m][n][j];
            }
        }
}

// ---------------------------------------------------------------------------
// kred: xp = sum of 4 split-K partials; also emit dt_lo (cols 0..63) as bf16.
// ---------------------------------------------------------------------------
__global__ __launch_bounds__(256) void kred(const float* __restrict__ part,
                                            float* __restrict__ xp,
                                            unsigned short* __restrict__ dtlo) {
    const int i = blockIdx.x * 256 + threadIdx.x;            // float4 idx, 196608 total
    const size_t stride = (size_t)ROWS_ * 96 / 4;
    const float4* p = (const float4*)part;
    float4 a = p[i], b = p[i + stride], c = p[i + 2 * stride], d = p[i + 3 * stride];
    float4 o;
    o.x = a.x + b.x + c.x + d.x;
    o.y = a.y + b.y + c.y + d.y;
    o.z = a.z + b.z + c.z + d.z;
    o.w = a.w + b.w + c.w + d.w;
    ((float4*)xp)[i] = o;
    const int c4 = i % 24, row = i / 24;
    if (c4 < 16) {
        ushort4 h;
        h.x = f2bf(o.x); h.y = f2bf(o.y); h.z = f2bf(o.z); h.w = f2bf(o.w);
        *(ushort4*)(dtlo + (size_t)row * 64 + c4 * 4) = h;
    }
}

// ---------------------------------------------------------------------------
// k4m: MFMA GEMM dt = dtlo @ WdtT^T (M=8192, N=2048, K=64) with fused
// softplus + per-128-col row sums -> psum[16][8192]. grid (64,16).
// ---------------------------------------------------------------------------
__global__ __launch_bounds__(256, 2) void k4m(const unsigned short* __restrict__ A,
                                              const unsigned short* __restrict__ B,
                                              const float* __restrict__ bdt,
                                              float* __restrict__ psum) {
    const int t = threadIdx.x;
    const int wid = t >> 6, lane = t & 63;
    const int m0 = blockIdx.x * 128;
    const int nb = blockIdx.y;
    const int wr = wid >> 1, wc = wid & 1;
    __shared__ unsigned short Als[128 * 64];
    __shared__ unsigned short Bls[128 * 64];
    __shared__ float srow[128][2];
    f32x4 acc[4][4];
    const f32x4 z4 = {0.f, 0.f, 0.f, 0.f};
#pragma unroll
    for (int m = 0; m < 4; ++m)
#pragma unroll
        for (int n = 0; n < 4; ++n) acc[m][n] = z4;
#pragma unroll
    for (int i = 0; i < 4; ++i) {
        const int c = wid * 256 + i * 64 + lane;
        const int row = c >> 3, eo = (c & 7) * 8;
        const int dst = (wid * 4 + i) * 1024;
        gload16(A + (size_t)(m0 + row) * 64 + eo, (char*)Als + dst);
        gload16(B + (size_t)(nb * 128 + row) * 64 + eo, (char*)Bls + dst);
    }
    __syncthreads();
    const int ar = wr * 64 + (lane & 15);
    const int br = wc * 64 + (lane & 15);
    const int kq = (lane >> 4) * 8;
    const int ccol = lane & 15;
    {
        bf16x8 af[4][2], bfr[4][2];
#pragma unroll
        for (int m = 0; m < 4; ++m)
#pragma unroll
            for (int kk = 0; kk < 2; ++kk)
                af[m][kk] = *(const bf16x8*)&Als[(ar + m * 16) * 64 + kk * 32 + kq];
#pragma unroll
        for (int n = 0; n < 4; ++n)
#pragma unroll
            for (int kk = 0; kk < 2; ++kk)
                bfr[n][kk] = *(const bf16x8*)&Bls[(br + n * 16) * 64 + kk * 32 + kq];
#pragma unroll
        for (int m = 0; m < 4; ++m)
#pragma unroll
            for (int n = 0; n < 4; ++n)
#pragma unroll
                for (int kk = 0; kk < 2; ++kk)
                    acc[m][n] = __builtin_amdgcn_mfma_f32_16x16x32_bf16(
                        af[m][kk], bfr[n][kk], acc[m][n], 0, 0, 0);
    }
    float bcol[4];
#pragma unroll
    for (int n = 0; n < 4; ++n) bcol[n] = bdt[nb * 128 + wc * 64 + n * 16 + ccol];
#pragma unroll
    for (int m = 0; m < 4; ++m)
#pragma unroll
        for (int j = 0; j < 4; ++j) {
            float s = 0.f;
#pragma unroll
            for (int n = 0; n < 4; ++n) {
                const float w = acc[m][n][j] + bcol[n];
                s += fmaxf(w, 0.f) + log1pf(expf(-fabsf(w)));   // softplus
            }
#pragma unroll
            for (int mask = 1; mask < 16; mask <<= 1) s += __shfl_xor(s, mask);
            if (ccol == 0)
                srow[wr * 64 + m * 16 + (lane >> 4) * 4 + j][wc] = s;
        }
    __syncthreads();
    if (t < 128)
        psum[(size_t)nb * ROWS_ + m0 + t] = srow[t][0] + srow[t][1];
}

// ---------------------------------------------------------------------------
// k4r: dtm = (sum of 16 psum)/2048; dec = exp(-dtm); u = xm * sum(Bp).
// ---------------------------------------------------------------------------
__global__ __launch_bounds__(256) void k4r(const float* __restrict__ psum,
                                           const float* __restrict__ xp,
                                           const float* __restrict__ xm,
                                           float* __restrict__ dec,
                                           float* __restrict__ u) {
    const int row = blockIdx.x * 256 + threadIdx.x;
    float tot = 0.f;
#pragma unroll
    for (int j = 0; j < 16; ++j) tot += psum[(size_t)j * ROWS_ + row];
    const float dtm = tot * (1.f / (float)DI_);
    float sBp = 0.f;
#pragma unroll
    for (int s = 0; s < DS_; ++s) sBp += xp[(size_t)row * 96 + DTR_ + s];
    dec[row] = expf(-dtm);
    u[row]   = xm[row] * sBp;
}

// ---------------------------------------------------------------------------
// k5: exact chunked scalar scan  S_l = d_l * S_{l-1} + u_l  (per batch).
// ---------------------------------------------------------------------------
__global__ __launch_bounds__(256) void k5_scan(const float* __restrict__ dec,
                                               const float* __restrict__ u,
                                               float* __restrict__ S) {
    const int t = threadIdx.x;
    __shared__ float aa[256], hh[256], init[256];
    const int b = t >> 7, c = t & 127;
    const int base = b * L_ + c * 32;
    float a = 1.f, h = 0.f;
    for (int i = 0; i < 32; ++i) {
        const float d = dec[base + i];
        h = h * d + u[base + i];
        a *= d;
    }
    aa[t] = a; hh[t] = h;
    __syncthreads();
    if (t < B_) {
        float run = 0.f;
        for (int cc = 0; cc < 128; ++cc) {
            const int tt = t * 128 + cc;
            init[tt] = run;
            run = hh[tt] + aa[tt] * run;
        }
    }
    __syncthreads();
    h = init[t];
    for (int i = 0; i < 32; ++i) {
        h = h * dec[base + i] + u[base + i];
        S[base + i] = h;
    }
}

// ---------------------------------------------------------------------------
// k6: per-row 16-vector v = Cp*S, LN stats over 16 (== LN over 2048 tile).
// ---------------------------------------------------------------------------
__global__ __launch_bounds__(256) void k6_v16(const float* __restrict__ xp,
                                              const float* __restrict__ S,
                                              float* __restrict__ v16) {
    const int row = blockIdx.x * 256 + threadIdx.x;
    const float s = S[row];
    float v[16], mu = 0.f;
#pragma unroll
    for (int i = 0; i < 16; ++i) {
        v[i] = xp[(size_t)row * 96 + DTR_ + DS_ + i] * s;
        mu += v[i];
    }
    mu *= (1.f / 16.f);
    float var = 0.f;
#pragma unroll
    for (int i = 0; i < 16; ++i) {
        const float d = v[i] - mu;
        var += d * d;
    }
    var *= (1.f / 16.f);
    const float rs = rsqrtf(var + 1e-5f);
#pragma unroll
    for (int i = 0; i < 16; ++i) v16[(size_t)row * 16 + i] = (v[i] - mu) * rs;
}

// ---------------------------------------------------------------------------
// kA7: Abf[row][i] = (v16[row][i&15]*g[i] + b[i]) * silu(z[row][i]), bf16.
// z = xz_bf cols 2048..4095.
// ---------------------------------------------------------------------------
__global__ __launch_bounds__(256) void kA7(const unsigned short* __restrict__ xz,
                                           const float* __restrict__ v16,
                                           const float* __restrict__ g,
                                           const float* __restrict__ bb,
                                           unsigned short* __restrict__ Abf) {
    const int row = blockIdx.x;
    const int t   = threadIdx.x;
    __shared__ float vrow[16];
    if (t < 16) vrow[t] = v16[row * 16 + t];
    __syncthreads();
    const int i0 = t * 8;
    const uint4 zraw = *(const uint4*)(xz + (size_t)row * NXZ_ + 2048 + i0);
    const unsigned short* zp = (const unsigned short*)&zraw;
    const float4 g0 = *(const float4*)(g + i0),  g1 = *(const float4*)(g + i0 + 4);
    const float4 b0 = *(const float4*)(bb + i0), b1 = *(const float4*)(bb + i0 + 4);
    const float gv[8] = {g0.x, g0.y, g0.z, g0.w, g1.x, g1.y, g1.z, g1.w};
    const float bv[8] = {b0.x, b0.y, b0.z, b0.w, b1.x, b1.y, b1.z, b1.w};
    unsigned short o[8];
#pragma unroll
    for (int j = 0; j < 8; ++j) {
        const int i = i0 + j;
        const float zf = bf2f(zp[j]);
        const float sz = zf / (1.f + expf(-zf));
        o[j] = f2bf((vrow[i & 15] * gv[j] + bv[j]) * sz);
    }
    *(uint4*)(Abf + (size_t)row * DI_ + i0) = *(const uint4*)o;
}

// ---------------------------------------------------------------------------
extern "C" void kernel_launch(void* const* d_in, const int* in_sizes, int n_in,
                              void* d_out, int out_size, void* d_ws, size_t ws_size,
                              hipStream_t stream) {
    const float* x    = (const float*)d_in[0];
    const float* Win  = (const float*)d_in[1];
    const float* Wcv  = (const float*)d_in[2];
    const float* Wxp  = (const float*)d_in[3];
    const float* Wdt  = (const float*)d_in[4];
    const float* bdt  = (const float*)d_in[5];
    const float* Wout = (const float*)d_in[6];
    const float* lng  = (const float*)d_in[7];
    const float* lnb  = (const float*)d_in[8];
    float* out = (float*)d_out;

    // ---- workspace layout (bytes), ~166 MB, lifetime-aliased ----
    char* base = (char*)d_ws;
    unsigned short* xz_bf   = (unsigned short*)(base + 0);           // 67.1 MB (k1->kA7)
    unsigned short* xsb     = (unsigned short*)(base + 67108864);    // 33.5 MB
    unsigned short* xbf     = (unsigned short*)(base + 100663296);   // 16.8 MB (dead after k1)
    unsigned short* Abf     = (unsigned short*)(base + 100663296);   // alias, 33.5 MB
    unsigned short* WoutT   = (unsigned short*)(base + 134217728);   // 4.2 MB
    unsigned short* WinT    = (unsigned short*)(base + 138412032);   // 8.4 MB
    unsigned short* WxpT    = (unsigned short*)(base + 146800640);   // 0.5 MB [128][2048]
    unsigned short* WdtT    = (unsigned short*)(base + 147324928);   // 0.26 MB [2048][64]
    float*          xp_part = (float*)(base + 147587072);            // 12.6 MB
    float*          xp      = (float*)(base + 160169984);            // 3.1 MB
    unsigned short* dtlo    = (unsigned short*)(base + 163315712);   // 1 MB [8192][64]
    float*          psum    = (float*)(base + 164364288);            // 0.5 MB [16][8192]
    float*          xm      = (float*)(base + 164888576);
    float*          dec     = (float*)(base + 164921344);
    float*          u       = (float*)(base + 164954112);
    float*          S       = (float*)(base + 164986880);
    float*          v16     = (float*)(base + 165019648);            // 0.5 MB

    kcvt<<<ROWS_ * D_ / 1024, 256, 0, stream>>>(x, xbf);
    ktrans<<<dim3(NXZ_ / 32, D_ / 32), 256, 0, stream>>>(Win, WinT, D_, NXZ_);
    ktrans<<<dim3(4, DI_ / 32), 256, 0, stream>>>(Wxp, WxpT, DI_, 96);
    ktrans<<<dim3(DI_ / 32, DTR_ / 32), 256, 0, stream>>>(Wdt, WdtT, DTR_, DI_);
    gemm_bf16<D_, true><<<dim3(ROWS_ / 128, NXZ_ / 128), 256, 0, stream>>>(
        xbf, WinT, xz_bf, NXZ_);
    ktrans<<<dim3(D_ / 32, DI_ / 32), 256, 0, stream>>>(Wout, WoutT, DI_, D_);
    k2_conv<<<ROWS_ / 16, 256, 0, stream>>>(xz_bf, Wcv, xsb, xm);
    k3m<<<dim3(ROWS_ / 128, 4), 256, 0, stream>>>(xsb, WxpT, xp_part);
    kred<<<ROWS_ * 96 / 4 / 256, 256, 0, stream>>>(xp_part, xp, dtlo);
    k4m<<<dim3(ROWS_ / 128, DI_ / 128), 256, 0, stream>>>(dtlo, WdtT, bdt, psum);
    k4r<<<ROWS_ / 256, 256, 0, stream>>>(psum, xp, xm, dec, u);
    k5_scan<<<1, 256, 0, stream>>>(dec, u, S);
    k6_v16<<<ROWS_ / 256, 256, 0, stream>>>(xp, S, v16);
    kA7<<<ROWS_, 256, 0, stream>>>(xz_bf, v16, lng, lnb, Abf);
    gemm_bf16<DI_, false><<<dim3(ROWS_ / 128, D_ / 128), 256, 0, stream>>>(
        Abf, WoutT, out, D_);
}